// Round 7
// baseline (147.570 us; speedup 1.0000x reference)
//
#include <hip/hip_runtime.h>
#include <stdint.h>

typedef unsigned long long u64;

#define A_TOTAL 43008
#define NB 16
#define NM 128
#define SPLIT 168                 // fused/epilogue blocks per batch (168*256 == A_TOTAL)
#define WPB 4

// Bit-exact fp32 division via Markstein sequence: v_rcp + 2 Newton + residual
// correction, all full-rate fmas. Correctly rounded (== v_div result) for
// normal-range operands: here num in [0, ~1e5], den in [~64, ~4e5]; num==0
// yields exactly +0.0. Avoids the ~50-cycle div_scale/div_fmas/div_fixup chain.
__device__ __forceinline__ float exact_div(float x, float y) {
    float r;
    asm("v_rcp_f32 %0, %1" : "=v"(r) : "v"(y));
    float e  = __builtin_fmaf(-y, r, 1.0f);
    r        = __builtin_fmaf(e, r, r);
    e        = __builtin_fmaf(-y, r, 1.0f);
    r        = __builtin_fmaf(e, r, r);
    float q  = x * r;
    float rs = __builtin_fmaf(-y, q, x);
    return __builtin_fmaf(rs, r, q);
}

// u64 cross-lane DPP max-merge helper (pairs stay inside aligned 8-lane octets).
__device__ __forceinline__ u64 dpp_u64(u64 v, const int ctrl) {
    int lo = (int)(unsigned)v, hi = (int)(unsigned)(v >> 32);
    int plo, phi;
    switch (ctrl) {
        case 0xB1:   // quad_perm [1,0,3,2] : xor 1
            plo = __builtin_amdgcn_update_dpp(lo, lo, 0xB1, 0xF, 0xF, false);
            phi = __builtin_amdgcn_update_dpp(hi, hi, 0xB1, 0xF, 0xF, false);
            break;
        case 0x4E:   // quad_perm [2,3,0,1] : xor 2
            plo = __builtin_amdgcn_update_dpp(lo, lo, 0x4E, 0xF, 0xF, false);
            phi = __builtin_amdgcn_update_dpp(hi, hi, 0x4E, 0xF, 0xF, false);
            break;
        default:     // 0x141 row_half_mirror : p -> 7-p within octet
            plo = __builtin_amdgcn_update_dpp(lo, lo, 0x141, 0xF, 0xF, false);
            phi = __builtin_amdgcn_update_dpp(hi, hi, 0x141, 0xF, 0xF, false);
            break;
    }
    return ((u64)(unsigned)phi << 32) | (unsigned)plo;
}

// Tiny prep: zero-init colfinal [NB*NM] + per-(batch,chunk) group bounds over
// 8-box chunks (for wave-uniform liveness skip). 8 blocks x 256.
__global__ __launch_bounds__(256) void prep_kernel(
    const float4* __restrict__ bboxes, u64* __restrict__ colfinal,
    float4* __restrict__ chunkbnd) {
#pragma clang fp contract(off)
    const int i = blockIdx.x * 256 + threadIdx.x;    // 0..2047
    colfinal[i] = 0ull;
    if (blockIdx.x == 0) {
        // thread t handles (b = t>>4, c = t&15): bounds over boxes c*8..c*8+7
        const int t = threadIdx.x;
        const int base = (t >> 4) * NM + (t & 15) * 8;
        float4 f = bboxes[base];
        float mnx = f.x, mny = f.y, mxx = f.z, mxy = f.w;
#pragma unroll
        for (int k = 1; k < 8; ++k) {
            float4 u = bboxes[base + k];
            mnx = fminf(mnx, u.x); mny = fminf(mny, u.y);
            mxx = fmaxf(mxx, u.z); mxy = fmaxf(mxy, u.w);
        }
        chunkbnd[t] = make_float4(mnx, mny, mxx, mxy);   // (min x1, min y1, max x2, max y2)
    }
}

// ---------------------------------------------------------------------------
// Fused IoU pass (R7): chunk-granular skip; live chunks run STRAIGHT-LINE.
//   History: R0 (no skip, branch-free) ran at ~102% VALUBusy / 70us. R1-R6
//   added per-box ballot guards: work dropped 87% but VALUBusy fell to 33-45%
//   (branches kill s_load hoisting / software pipelining; each live box paid
//   serialized latency). R7 keeps ONLY the chunk-level skip (one branch per
//   chunk, ~48% of chunk-visits skipped) and computes all 8 boxes of a live
//   chunk unconditionally — R0's proven-bit-exact inner loop at full issue.
//   - grid (168, NB), 4 waves/block, b = blockIdx.y (K$ locality; R3 proved
//     cross-batch interleave thrashes the scalar cache).
//   - strided unit map w = blockIdx.x + wv*168 (level-2 units one-per-block);
//     no __syncthreads; waves retire independently.
//   - value-preserving: dead lanes in a live chunk produce iou == +0.0
//     bit-exactly (never wins under strict '>'; row best init (0.0, m=0) ==
//     ref argmax of an all-zero row). Col keys with iou 0.0 carry valid
//     anchor ids but always lose: every box's true column max is > 0
//     (512px level-2 anchors cover the whole image). Skipped chunks emit
//     nothing; the argmax anchor's wave is always live for that chunk.
//   - in-loop predicated colfinal atomicMax (R4-proven; R6 showed deferred+
//     filtered atomics HURT via cross-XCD read traffic — reverted).
//   - areaB inline from box coords (R6-proven bit-identical to prep's form).
// ---------------------------------------------------------------------------
__global__ __launch_bounds__(256) void fused_kernel(
    const float4* __restrict__ anchors, const float4* __restrict__ bbv,
    const float4* __restrict__ chunkbnd,
    u64* __restrict__ rowkey,        // [NB][A_TOTAL] (iou_bits<<32)|m
    u64* __restrict__ colfinal) {    // [NB][NM] atomicMax table
#pragma clang fp contract(off)
    const int b = blockIdx.y, tid = threadIdx.x;
    const int lane = tid & 63, wv = tid >> 6;
    const int bi = lane >> 3, part = lane & 7;
    const int rbase = part * 8;

    __shared__ float s_col[WPB][8][65];   // chunk transpose (2-way = free)

    const int w = blockIdx.x + wv * SPLIT;     // strided: L2 units 1-per-block
    const int abase = w * 64;

    // this wave's 64 anchors, converted once
    float4 an = anchors[abase + lane];
    float hw = an.z * 0.5f, hh = an.w * 0.5f;
    float ax1 = an.x - hw, ay1 = an.y - hh;
    float ax2 = an.x + hw, ay2 = an.y + hh;
    float areaA = (ax2 - ax1) * (ay2 - ay1);

    const float4* box = bbv + (size_t)b * NM;      // uniform -> s_load_dwordx4
    const float4* cb  = chunkbnd + (b << 4);
    u64* colf = colfinal + (size_t)b * NM;

    // up-front chunk liveness mask (16 ballots, branch-free buildup)
    unsigned cmask = 0;
#pragma unroll
    for (int c = 0; c < 16; ++c) {
        float4 gb = cb[c];
        bool cl = (gb.z > ax1) & (gb.x < ax2) & (gb.w > ay1) & (gb.y < ay2);
        if (__ballot(cl) != 0ull) cmask |= 1u << c;
    }

    float best_v = 0.0f; int best_m = 0;           // == ref argmax of zero row

    while (cmask) {
        const int c = __builtin_ctz(cmask);
        cmask &= cmask - 1;
        const int m0 = c * 8;

        // straight-line 8-box compute: all s_loads hoist, chains pipeline
#pragma unroll
        for (int i = 0; i < 8; ++i) {
            const float4 bx = box[m0 + i];         // one s_load_dwordx4
            const float areaB = (bx.z - bx.x) * (bx.w - bx.y);
            float ltx = fmaxf(ax1, bx.x), lty = fmaxf(ay1, bx.y);
            float rbx = fminf(ax2, bx.z), rby = fminf(ay2, bx.w);
            float wx = fmaxf(rbx - ltx, 0.0f), wy = fmaxf(rby - lty, 0.0f);
            float inter = wx * wy;
            float iou = exact_div(inter, (areaA + areaB) - inter);
            if (iou > best_v) { best_v = iou; best_m = m0 + i; }  // first m on tie
            s_col[wv][i][lane] = iou;
        }

        // col chunk reduce: 8 lanes (parts) per box, 8 serial entries each
        float v = -1.0f; int tb = 0;
#pragma unroll
        for (int t = 0; t < 8; ++t) {              // ascending anchor
            float o = s_col[wv][bi][rbase + t];
            if (o > v) { v = o; tb = t; }          // strict > : smallest t
        }
        unsigned aidx = (unsigned)(abase + rbase + tb);
        u64 key = ((u64)__float_as_uint(v) << 32) | (u64)(unsigned)(~aidx);
        { u64 o = dpp_u64(key, 0xB1);  if (o > key) key = o; }
        { u64 o = dpp_u64(key, 0x4E);  if (o > key) key = o; }
        { u64 o = dpp_u64(key, 0x141); if (o > key) key = o; }
        if (part == 0)
            atomicMax(&colf[m0 + bi], key);        // fire-and-forget
    }

    rowkey[(size_t)b * A_TOTAL + abase + lane] =
        ((u64)__float_as_uint(best_v) << 32) | (u64)(unsigned)best_m;
}

// Streaming epilogue (proven): per-block override window + score + gather.
__global__ __launch_bounds__(256) void epilogue_kernel(
    const float4* __restrict__ bboxes, const int* __restrict__ labels,
    const u64* __restrict__ colfinal, const u64* __restrict__ rowkey,
    float* __restrict__ out_scores, float4* __restrict__ out_matched) {
#pragma clang fp contract(off)
    const int b = blockIdx.y, tid = threadIdx.x;
    const int a0 = blockIdx.x * 256, a = a0 + tid;   // A_TOTAL == 168*256

    __shared__ float4 sbox[NM];
    __shared__ float  s_cm[NM];
    __shared__ int    s_lab[NM];
    __shared__ int    ovr[256];
    ovr[tid] = -1;

    int my_ca = -1;
    if (tid < NM) {
        u64 k = colfinal[b * NM + tid];
        s_cm[tid] = __uint_as_float((unsigned)(k >> 32));
        my_ca = ~((int)(unsigned)(k & 0xFFFFFFFFull));   // recover anchor idx
        sbox[tid]  = bboxes[b * NM + tid];
        s_lab[tid] = labels[b * NM + tid];
    }
    __syncthreads();
    if (tid < NM && my_ca >= a0 && my_ca < a0 + 256)
        atomicMax(&ovr[my_ca - a0], tid);                // later j wins == max j
    __syncthreads();

    u64 rk = rowkey[(size_t)b * A_TOTAL + a];
    float best = __uint_as_float((unsigned)(rk >> 32));
    int   bi   = (int)(rk & 0xFFFFFFFFull);

    int o = ovr[tid];
    if (o >= 0) { bi = o; best = s_cm[o]; }

    float denom = fmaxf(s_cm[bi], 0.3f);        // IOU_THR
    float val   = (best < 0.15f) ? 0.0f : best; // IOU_THR * 0.5
    float score = val / denom;
    if (s_lab[bi] <= 0) score = 0.0f;

    out_scores[(size_t)b * A_TOTAL + a]  = score;
    out_matched[(size_t)b * A_TOTAL + a] = sbox[bi];
}

extern "C" void kernel_launch(void* const* d_in, const int* in_sizes, int n_in,
                              void* d_out, int out_size, void* d_ws, size_t ws_size,
                              hipStream_t stream) {
    const int*    labels  = (const int*)d_in[0];     // [NB, NM] int32
    const float4* bboxes  = (const float4*)d_in[1];  // [NB, NM, 4] xyxy
    const float4* anchors = (const float4*)d_in[2];  // [A_TOTAL, 4] cxcywh

    float* out = (float*)d_out;                      // scores [NB,A], matched [NB,A,4]

    char* ws = (char*)d_ws;
    u64*    rowkey   = (u64*)ws;                     ws += (size_t)NB * A_TOTAL * 8;
    u64*    colfinal = (u64*)ws;                     ws += (size_t)NB * NM * 8;
    float4* chunkbnd = (float4*)ws;                  // [NB*16]

    prep_kernel<<<(NB * NM) / 256, 256, 0, stream>>>(bboxes, colfinal, chunkbnd);

    dim3 g(SPLIT, NB);
    fused_kernel<<<g, 256, 0, stream>>>(anchors, bboxes, chunkbnd,
                                        rowkey, colfinal);
    epilogue_kernel<<<g, 256, 0, stream>>>(
        bboxes, labels, colfinal, rowkey,
        out, (float4*)(out + (size_t)NB * A_TOTAL));
}

// Round 8
// 109.491 us; speedup vs baseline: 1.3478x; 1.3478x over previous
//
#include <hip/hip_runtime.h>
#include <stdint.h>

typedef unsigned long long u64;

#define A_TOTAL 43008
#define NB 16
#define NM 128
#define SPLIT 168                 // fused/epilogue blocks per batch (168*256 == A_TOTAL)
#define WPB 4

// Bit-exact fp32 division via Markstein sequence: v_rcp + 2 Newton + residual
// correction, all full-rate fmas. Correctly rounded (== v_div result) for
// normal-range operands: here num in [0, ~1e5], den in [~64, ~4e5]; num==0
// yields exactly +0.0. Avoids the ~50-cycle div_scale/div_fmas/div_fixup chain.
__device__ __forceinline__ float exact_div(float x, float y) {
    float r;
    asm("v_rcp_f32 %0, %1" : "=v"(r) : "v"(y));
    float e  = __builtin_fmaf(-y, r, 1.0f);
    r        = __builtin_fmaf(e, r, r);
    e        = __builtin_fmaf(-y, r, 1.0f);
    r        = __builtin_fmaf(e, r, r);
    float q  = x * r;
    float rs = __builtin_fmaf(-y, q, x);
    return __builtin_fmaf(rs, r, q);
}

// u64 cross-lane DPP max-merge helper (pairs stay inside aligned 8-lane octets).
__device__ __forceinline__ u64 dpp_u64(u64 v, const int ctrl) {
    int lo = (int)(unsigned)v, hi = (int)(unsigned)(v >> 32);
    int plo, phi;
    switch (ctrl) {
        case 0xB1:   // quad_perm [1,0,3,2] : xor 1
            plo = __builtin_amdgcn_update_dpp(lo, lo, 0xB1, 0xF, 0xF, false);
            phi = __builtin_amdgcn_update_dpp(hi, hi, 0xB1, 0xF, 0xF, false);
            break;
        case 0x4E:   // quad_perm [2,3,0,1] : xor 2
            plo = __builtin_amdgcn_update_dpp(lo, lo, 0x4E, 0xF, 0xF, false);
            phi = __builtin_amdgcn_update_dpp(hi, hi, 0x4E, 0xF, 0xF, false);
            break;
        default:     // 0x141 row_half_mirror : p -> 7-p within octet
            plo = __builtin_amdgcn_update_dpp(lo, lo, 0x141, 0xF, 0xF, false);
            phi = __builtin_amdgcn_update_dpp(hi, hi, 0x141, 0xF, 0xF, false);
            break;
    }
    return ((u64)(unsigned)phi << 32) | (unsigned)plo;
}

// ---------------------------------------------------------------------------
// Prep (R8): per-batch y-sort of boxes so chunks of 8 are spatially coherent.
// One block per batch, 128 threads. Rank-sort in LDS (ties by index -> valid
// permutation). Outputs: bsorted[b][128] (boxes in sorted order), origidx
// (sorted pos -> original m), chunkbnd over SORTED chunks (now ~196px tall
// instead of whole-image: this is what makes the fused chunk-skip actually
// filter — R7 measured 89% live chunks with unsorted chunk bounds).
// Also zero-inits colfinal.
// ---------------------------------------------------------------------------
__global__ __launch_bounds__(128) void prep_kernel(
    const float4* __restrict__ bboxes, u64* __restrict__ colfinal,
    float4* __restrict__ bsorted, int* __restrict__ origidx,
    float4* __restrict__ chunkbnd) {
#pragma clang fp contract(off)
    const int b = blockIdx.x, i = threadIdx.x;     // batch, box
    __shared__ float  s_y[NM];
    __shared__ float4 s_box[NM];
    __shared__ int    s_oi[NM];

    colfinal[b * NM + i] = 0ull;
    float4 v = bboxes[b * NM + i];
    s_y[i] = v.y;
    __syncthreads();

    const float myy = v.y;
    int rank = 0;
    for (int j = 0; j < NM; ++j) {                 // broadcast reads, cheap
        float yj = s_y[j];
        rank += (yj < myy) || (yj == myy && j < i);
    }
    s_box[rank] = v;                               // distinct ranks: scatter ok
    s_oi[rank]  = i;
    __syncthreads();

    bsorted[b * NM + i] = s_box[i];
    origidx[b * NM + i] = s_oi[i];
    if (i < 16) {
        float4 f = s_box[i * 8];
        float mnx = f.x, mny = f.y, mxx = f.z, mxy = f.w;
#pragma unroll
        for (int k = 1; k < 8; ++k) {
            float4 u = s_box[i * 8 + k];
            mnx = fminf(mnx, u.x); mny = fminf(mny, u.y);
            mxx = fmaxf(mxx, u.z); mxy = fmaxf(mxy, u.w);
        }
        chunkbnd[b * 16 + i] = make_float4(mnx, mny, mxx, mxy);
    }
}

// ---------------------------------------------------------------------------
// Fused IoU pass (R8) = R7's straight-line chunk body (83% VALUBusy proven)
// over Y-SORTED chunks (chunk-skip now filters ~3x: tight y-bounds).
//   - grid (168, NB), 4 waves/block, b = blockIdx.y (K$ locality, R3-proven);
//     strided unit map w = blockIdx.x + wv*168; no __syncthreads anywhere.
//   - ROW argmax via u64 key max (iou_bits<<32)|~orig_m: order-independent,
//     tie -> smallest original m == reference first-occurrence. Init
//     (0.0, ~0) == ref argmax of all-zero row; zero-iou boxes never change it.
//   - COL: per-wave DPP octet merge -> atomicMax on ORIGINAL column (origidx
//     via LDS, benign redundant per-wave write, no barrier). Zero-iou octet
//     keys gated off (bit-identical: every column's true max > 0 — level-2
//     anchors cover the image and that wave is chunk-live by construction).
//   - value-preserving skip: lanes not overlapping the chunk bound produce
//     iou == +0.0 bit-exactly for every box in it; such keys never win.
// ---------------------------------------------------------------------------
__global__ __launch_bounds__(256) void fused_kernel(
    const float4* __restrict__ anchors, const float4* __restrict__ bsorted,
    const int* __restrict__ origidx, const float4* __restrict__ chunkbnd,
    u64* __restrict__ rowkey,        // [NB][A_TOTAL] (iou_bits<<32)|m
    u64* __restrict__ colfinal) {    // [NB][NM] atomicMax table
#pragma clang fp contract(off)
    const int b = blockIdx.y, tid = threadIdx.x;
    const int lane = tid & 63, wv = tid >> 6;
    const int bi = lane >> 3, part = lane & 7;
    const int rbase = part * 8;

    __shared__ float s_col[WPB][8][65];   // chunk transpose (2-way = free)
    __shared__ int   s_oc[NM];            // sorted pos -> original column

    const int w = blockIdx.x + wv * SPLIT;     // strided: L2 units 1-per-block
    const int abase = w * 64;

    const float4* box = bsorted + (size_t)b * NM;  // uniform -> s_load_dwordx4
    const int*    oi  = origidx + (size_t)b * NM;
    const float4* cb  = chunkbnd + (b << 4);
    u64* colf = colfinal + (size_t)b * NM;

    // each wave writes the full table itself (identical values across waves ->
    // benign race; a wave's own reads follow its own writes, no barrier)
    s_oc[lane]      = oi[lane];
    s_oc[64 + lane] = oi[64 + lane];

    // this wave's 64 anchors, converted once
    float4 an = anchors[abase + lane];
    float hw = an.z * 0.5f, hh = an.w * 0.5f;
    float ax1 = an.x - hw, ay1 = an.y - hh;
    float ax2 = an.x + hw, ay2 = an.y + hh;
    float areaA = (ax2 - ax1) * (ay2 - ay1);

    // up-front chunk liveness mask (16 ballots, branch-free buildup)
    unsigned cmask = 0;
#pragma unroll
    for (int c = 0; c < 16; ++c) {
        float4 gb = cb[c];
        bool cl = (gb.z > ax1) & (gb.x < ax2) & (gb.w > ay1) & (gb.y < ay2);
        if (__ballot(cl) != 0ull) cmask |= 1u << c;
    }

    u64 best_key = 0x00000000FFFFFFFFull;          // (iou=0.0, ~m=~0 -> m=0)

    while (cmask) {
        const int c = __builtin_ctz(cmask);
        cmask &= cmask - 1;
        const int m0 = c * 8;

        // straight-line 8-box compute: all s_loads hoist, chains pipeline
#pragma unroll
        for (int i = 0; i < 8; ++i) {
            const float4 bx = box[m0 + i];         // s_load_dwordx4
            const int    om = oi[m0 + i];          // s_load (wave-uniform)
            const float areaB = (bx.z - bx.x) * (bx.w - bx.y);
            float ltx = fmaxf(ax1, bx.x), lty = fmaxf(ay1, bx.y);
            float rbx = fminf(ax2, bx.z), rby = fminf(ay2, bx.w);
            float wx = fmaxf(rbx - ltx, 0.0f), wy = fmaxf(rby - lty, 0.0f);
            float inter = wx * wy;
            float iou = exact_div(inter, (areaA + areaB) - inter);
            u64 bk = ((u64)__float_as_uint(iou) << 32) | (u64)(unsigned)(~om);
            if (bk > best_key) best_key = bk;      // tie -> smallest orig m
            s_col[wv][i][lane] = iou;
        }

        // col chunk reduce: 8 lanes (parts) per box, 8 serial entries each
        float v = -1.0f; int tb = 0;
#pragma unroll
        for (int t = 0; t < 8; ++t) {              // ascending anchor
            float o = s_col[wv][bi][rbase + t];
            if (o > v) { v = o; tb = t; }          // strict > : smallest t
        }
        unsigned aidx = (unsigned)(abase + rbase + tb);
        u64 key = ((u64)__float_as_uint(v) << 32) | (u64)(unsigned)(~aidx);
        { u64 o = dpp_u64(key, 0xB1);  if (o > key) key = o; }
        { u64 o = dpp_u64(key, 0x4E);  if (o > key) key = o; }
        { u64 o = dpp_u64(key, 0x141); if (o > key) key = o; }
        const int ocol = s_oc[m0 + bi];            // ds_read, broadcast groups
        if (part == 0 && (key >> 32) != 0)         // zero-iou keys never win
            atomicMax(&colf[ocol], key);
    }

    rowkey[(size_t)b * A_TOTAL + abase + lane] =
        (best_key & 0xFFFFFFFF00000000ull) |
        (u64)(unsigned)(~(unsigned)best_key);      // (iou_bits<<32) | m
}

// Streaming epilogue (proven): per-block override window + score + gather.
__global__ __launch_bounds__(256) void epilogue_kernel(
    const float4* __restrict__ bboxes, const int* __restrict__ labels,
    const u64* __restrict__ colfinal, const u64* __restrict__ rowkey,
    float* __restrict__ out_scores, float4* __restrict__ out_matched) {
#pragma clang fp contract(off)
    const int b = blockIdx.y, tid = threadIdx.x;
    const int a0 = blockIdx.x * 256, a = a0 + tid;   // A_TOTAL == 168*256

    __shared__ float4 sbox[NM];
    __shared__ float  s_cm[NM];
    __shared__ int    s_lab[NM];
    __shared__ int    ovr[256];
    ovr[tid] = -1;

    int my_ca = -1;
    if (tid < NM) {
        u64 k = colfinal[b * NM + tid];
        s_cm[tid] = __uint_as_float((unsigned)(k >> 32));
        my_ca = ~((int)(unsigned)(k & 0xFFFFFFFFull));   // recover anchor idx
        sbox[tid]  = bboxes[b * NM + tid];
        s_lab[tid] = labels[b * NM + tid];
    }
    __syncthreads();
    if (tid < NM && my_ca >= a0 && my_ca < a0 + 256)
        atomicMax(&ovr[my_ca - a0], tid);                // later j wins == max j
    __syncthreads();

    u64 rk = rowkey[(size_t)b * A_TOTAL + a];
    float best = __uint_as_float((unsigned)(rk >> 32));
    int   bi   = (int)(rk & 0xFFFFFFFFull);

    int o = ovr[tid];
    if (o >= 0) { bi = o; best = s_cm[o]; }

    float denom = fmaxf(s_cm[bi], 0.3f);        // IOU_THR
    float val   = (best < 0.15f) ? 0.0f : best; // IOU_THR * 0.5
    float score = val / denom;
    if (s_lab[bi] <= 0) score = 0.0f;

    out_scores[(size_t)b * A_TOTAL + a]  = score;
    out_matched[(size_t)b * A_TOTAL + a] = sbox[bi];
}

extern "C" void kernel_launch(void* const* d_in, const int* in_sizes, int n_in,
                              void* d_out, int out_size, void* d_ws, size_t ws_size,
                              hipStream_t stream) {
    const int*    labels  = (const int*)d_in[0];     // [NB, NM] int32
    const float4* bboxes  = (const float4*)d_in[1];  // [NB, NM, 4] xyxy
    const float4* anchors = (const float4*)d_in[2];  // [A_TOTAL, 4] cxcywh

    float* out = (float*)d_out;                      // scores [NB,A], matched [NB,A,4]

    char* ws = (char*)d_ws;
    u64*    rowkey   = (u64*)ws;                     ws += (size_t)NB * A_TOTAL * 8;
    u64*    colfinal = (u64*)ws;                     ws += (size_t)NB * NM * 8;
    float4* bsorted  = (float4*)ws;                  ws += (size_t)NB * NM * 16;
    int*    origidx  = (int*)ws;                     ws += (size_t)NB * NM * 4;
    float4* chunkbnd = (float4*)ws;                  // [NB*16]

    prep_kernel<<<NB, 128, 0, stream>>>(bboxes, colfinal, bsorted, origidx,
                                        chunkbnd);

    dim3 g(SPLIT, NB);
    fused_kernel<<<g, 256, 0, stream>>>(anchors, bsorted, origidx, chunkbnd,
                                        rowkey, colfinal);
    epilogue_kernel<<<g, 256, 0, stream>>>(
        bboxes, labels, colfinal, rowkey,
        out, (float4*)(out + (size_t)NB * A_TOTAL));
}